// Round 21
// baseline (33.562 us; speedup 1.0000x reference)
//
#include <hip/hip_runtime.h>

#define NCH 8
#define CACHE 6   // float4 per lane -> 384 slots; covers segments to 192 pts (max ~190)

typedef float v4f __attribute__((ext_vector_type(4)));

__device__ __forceinline__ v4f norm4(const float4& v, const float4& m, const float4& d) {
    v4f o;
    o.x = (v.x - m.x) * d.x;
    o.y = (v.y - m.y) * d.y;
    o.z = (v.z - m.z) * d.z;
    o.w = (v.w - m.w) * d.w;
    return o;
}

// Full wave-cooperative lower_bound (fallback path): 4 memory rounds for n=2M.
__device__ __forceinline__ int wave_lower_bound(const int* __restrict__ a, int n, int key,
                                                int lane) {
    int lo = 0, len = n;
    while (len > 64) {
        int step = (len + 63) >> 6;                       // ceil(len/64)
        int p = lo + lane * step;
        int v = (p < lo + len) ? a[p] : 0x7fffffff;
        unsigned long long bal = __ballot(v < key);
        int cnt = __popcll(bal);                          // preds form a prefix (sorted)
        if (cnt == 0) return lo;
        int nlo = lo + (cnt - 1) * step + 1;
        int nhi = lo + len;
        int cap = lo + cnt * step;
        if (cnt < 64 && cap < nhi) nhi = cap;
        lo = nlo; len = nhi - nlo;
    }
    int v = (lane < len) ? a[lo + lane] : 0x7fffffff;
    unsigned long long bal = __ballot(v < key);
    return lo + __popcll(bal);
}

// Guess-based windowed search: i_frustum is near-uniform, so start(key) ~ key*n/F
// (max prefix deviation ~1800 for multinomial counts; window +-2048 covers it).
// One 64-probe window round brackets s into <=64 candidates; one final round
// resolves it. Wave-uniform conclusiveness check falls back to the full search,
// so the result is correct for ANY sorted array (no data-dependence).
__device__ __forceinline__ int wave_find_start(const int* __restrict__ a, int n, int F,
                                               int key, int lane) {
    const int g = (int)(((long long)key * n) / F);
    const int p = min(max(g - 2048 + lane * 64, 0), n - 1);
    const int v = a[p];
    const int cnt = __popcll(__ballot(v < key));   // monotone predicate, prefix count

    if (cnt == 0) {
        const int p0 = min(max(g - 2048, 0), n - 1);
        if (p0 == 0) return 0;                     // s <= 0 -> 0 (conclusive)
        return wave_lower_bound(a, n, key, lane);  // boundary left of window
    }
    if (cnt == 64) {
        const int p63 = min(max(g - 2048 + 63 * 64, 0), n - 1);
        if (p63 == n - 1) return n;                // key beyond all (conclusive)
        return wave_lower_bound(a, n, key, lane);  // boundary right of window
    }
    // Bracketed: s in (probe_{cnt-1}, probe_cnt].
    const int lo2 = min(max(g - 2048 + (cnt - 1) * 64, 0), n - 1) + 1;
    const int hi2 = min(max(g - 2048 + cnt * 64, 0), n - 1);
    const int len = hi2 - lo2 + 1;                 // <= 64
    const int v2 = (lane < len) ? a[lo2 + lane] : 0x7fffffff;
    return lo2 + __popcll(__ballot(v2 < key));
}

// One WAVE per frustum, fused search+stats+normalize (R19 structure: CACHE=6,
// 256-thread blocks, eager full reduce). R21 delta: windowed guess-based search
// (2 memory rounds typical vs 4) + counts load hoisted ahead of the search.
__global__ __launch_bounds__(256) void k_fused(
    const float* __restrict__ pc, const int* __restrict__ i_frustum,
    const float* __restrict__ counts, int n, int F,
    float* __restrict__ out_mean, float* __restrict__ out_std,
    float* __restrict__ out_max, float* __restrict__ out_pcn)
{
    const int wid = (blockIdx.x * blockDim.x + threadIdx.x) >> 6;  // global wave id
    if (wid >= F) return;                                          // wave-uniform exit
    const int lane = threadIdx.x & 63;

    const float cnt = counts[wid];   // issued before the search; in flight during it
    const int s = wave_find_start(i_frustum, n, F, wid, lane);
    const int e = s + (int)cnt;      // counts are small integers, exact in float

    const float4* __restrict__ pc4 = reinterpret_cast<const float4*>(pc);
    v4f* __restrict__ out4 = reinterpret_cast<v4f*>(out_pcn);

    const int b = s * 2, E = e * 2;  // float4-granular range (NCH=8 -> 2 float4/point)
    const int lim = max(E - 1, 0);   // clamp target (empty segment -> index 0, masked off)

    float4 sum = {0.f, 0.f, 0.f, 0.f};
    float4 sq  = {0.f, 0.f, 0.f, 0.f};
    float4 mx  = {0.f, 0.f, 0.f, 0.f};  // 0-init == scatter-max onto zeros (include_self)
    float4 c[CACHE];

    // Phase 1: unconditional clamped loads -> issue back-to-back.
    {
        int k = b + lane;
        #pragma unroll
        for (int u = 0; u < CACHE; ++u) {
            c[u] = pc4[min(k, lim)];
            k += 64;
        }
    }
    // Phase 2: branchless masked accumulate (0 = identity for sum/sq and max-vs-0).
    {
        int k = b + lane;
        #pragma unroll
        for (int u = 0; u < CACHE; ++u) {
            const bool in = k < E;
            float vx = in ? c[u].x : 0.f, vy = in ? c[u].y : 0.f;
            float vz = in ? c[u].z : 0.f, vw = in ? c[u].w : 0.f;
            sum.x += vx; sq.x += vx * vx; mx.x = fmaxf(mx.x, vx);
            sum.y += vy; sq.y += vy * vy; mx.y = fmaxf(mx.y, vy);
            sum.z += vz; sq.z += vz * vz; mx.z = fmaxf(mx.z, vz);
            sum.w += vw; sq.w += vw * vw; mx.w = fmaxf(mx.w, vw);
            k += 64;
        }
        for (int kk = b + lane + CACHE * 64; kk < E; kk += 64) {  // tail (>192-pt segments)
            float4 v = pc4[kk];
            sum.x += v.x; sq.x += v.x * v.x; mx.x = fmaxf(mx.x, v.x);
            sum.y += v.y; sq.y += v.y * v.y; mx.y = fmaxf(mx.y, v.y);
            sum.z += v.z; sq.z += v.z * v.z; mx.z = fmaxf(mx.z, v.z);
            sum.w += v.w; sq.w += v.w * v.w; mx.w = fmaxf(mx.w, v.w);
        }
    }

    // Lane parity p = lane&1 owns channels [4p, 4p+4). Reduce lanes differing in bits 1..5.
    #pragma unroll
    for (int m = 2; m <= 32; m <<= 1) {
        sum.x += __shfl_xor(sum.x, m, 64);
        sum.y += __shfl_xor(sum.y, m, 64);
        sum.z += __shfl_xor(sum.z, m, 64);
        sum.w += __shfl_xor(sum.w, m, 64);
        sq.x  += __shfl_xor(sq.x,  m, 64);
        sq.y  += __shfl_xor(sq.y,  m, 64);
        sq.z  += __shfl_xor(sq.z,  m, 64);
        sq.w  += __shfl_xor(sq.w,  m, 64);
        mx.x = fmaxf(mx.x, __shfl_xor(mx.x, m, 64));
        mx.y = fmaxf(mx.y, __shfl_xor(mx.y, m, 64));
        mx.z = fmaxf(mx.z, __shfl_xor(mx.z, m, 64));
        mx.w = fmaxf(mx.w, __shfl_xor(mx.w, m, 64));
    }

    // Every lane holds its parity-group totals; compute stats redundantly (cheap).
    const float invc = 1.0f / fmaxf(cnt, 1.0f);
    float4 mean, sd, dv;
    mean.x = sum.x * invc; mean.y = sum.y * invc; mean.z = sum.z * invc; mean.w = sum.w * invc;
    float vx = fmaxf(sq.x * invc - mean.x * mean.x, 0.0f);
    float vy = fmaxf(sq.y * invc - mean.y * mean.y, 0.0f);
    float vz = fmaxf(sq.z * invc - mean.z * mean.z, 0.0f);
    float vw = fmaxf(sq.w * invc - mean.w * mean.w, 0.0f);
    sd.x = sqrtf(vx); sd.y = sqrtf(vy); sd.z = sqrtf(vz); sd.w = sqrtf(vw);
    dv.x = 1.0f / (sd.x > 0.f ? sd.x : 1.f);
    dv.y = 1.0f / (sd.y > 0.f ? sd.y : 1.f);
    dv.z = 1.0f / (sd.z > 0.f ? sd.z : 1.f);
    dv.w = 1.0f / (sd.w > 0.f ? sd.w : 1.f);

    if (lane < 2) {  // lane 0 -> channels 0-3, lane 1 -> channels 4-7
        reinterpret_cast<float4*>(out_mean + (size_t)wid * NCH)[lane] = mean;
        reinterpret_cast<float4*>(out_std  + (size_t)wid * NCH)[lane] = sd;
        reinterpret_cast<float4*>(out_max  + (size_t)wid * NCH)[lane] = mx;
    }

    // Normalize from the register cache; NT stores (output never re-read).
    {
        int k = b + lane;
        #pragma unroll
        for (int u = 0; u < CACHE; ++u) {
            if (k < E) {
                v4f o = norm4(c[u], mean, dv);
                __builtin_nontemporal_store(o, &out4[k]);
            }
            k += 64;
        }
        for (int kk = b + lane + CACHE * 64; kk < E; kk += 64) {  // tail
            v4f o = norm4(pc4[kk], mean, dv);
            __builtin_nontemporal_store(o, &out4[kk]);
        }
    }
}

extern "C" void kernel_launch(void* const* d_in, const int* in_sizes, int n_in,
                              void* d_out, int out_size, void* d_ws, size_t ws_size,
                              hipStream_t stream) {
    const float* pc        = (const float*)d_in[0];
    const int*   i_frustum = (const int*)d_in[1];
    const float* counts    = (const float*)d_in[3];

    int n = in_sizes[0] / NCH;   // 2,000,000 points
    int F = in_sizes[3];         // 14,400 frustums

    float* out_mean = (float*)d_out;
    float* out_std  = out_mean + (size_t)F * NCH;
    float* out_max  = out_std  + (size_t)F * NCH;
    float* out_pcn  = out_max  + (size_t)F * NCH;

    int waves_per_block = 256 / 64;
    int blocks = (F + waves_per_block - 1) / waves_per_block;
    k_fused<<<blocks, 256, 0, stream>>>(pc, i_frustum, counts, n, F,
                                        out_mean, out_std, out_max, out_pcn);
}

// Round 22
// 29.456 us; speedup vs baseline: 1.1394x; 1.1394x over previous
//
#include <hip/hip_runtime.h>

#define NCH 8
#define CACHE 6   // float4 per lane per segment -> 384 slots; covers <=192 pts (max ~190)

typedef float v4f __attribute__((ext_vector_type(4)));

__device__ __forceinline__ v4f norm4(const float4& v, const float4& m, const float4& d) {
    v4f o;
    o.x = (v.x - m.x) * d.x;
    o.y = (v.y - m.y) * d.y;
    o.z = (v.z - m.z) * d.z;
    o.w = (v.w - m.w) * d.w;
    return o;
}

// Wave-cooperative lower_bound: smallest idx with a[idx] >= key. 4 memory rounds for n=2M.
__device__ __forceinline__ int wave_lower_bound(const int* __restrict__ a, int n, int key,
                                                int lane) {
    int lo = 0, len = n;
    while (len > 64) {
        int step = (len + 63) >> 6;                       // ceil(len/64)
        int p = lo + lane * step;
        int v = (p < lo + len) ? a[p] : 0x7fffffff;
        unsigned long long bal = __ballot(v < key);
        int cnt = __popcll(bal);                          // preds form a prefix (sorted)
        if (cnt == 0) return lo;
        int nlo = lo + (cnt - 1) * step + 1;
        int nhi = lo + len;
        int cap = lo + cnt * step;
        if (cnt < 64 && cap < nhi) nhi = cap;
        lo = nlo; len = nhi - nlo;
    }
    int v = (lane < len) ? a[lo + lane] : 0x7fffffff;
    unsigned long long bal = __ballot(v < key);
    return lo + __popcll(bal);
}

// Masked accumulate of one cached segment slice.
#define ACC(creg, kvar, Evar)                                                  \
    {                                                                          \
        const bool in = (kvar) < (Evar);                                       \
        float ax = in ? (creg).x : 0.f, ay = in ? (creg).y : 0.f;              \
        float az = in ? (creg).z : 0.f, aw = in ? (creg).w : 0.f;              \
        sum.x += ax; sq.x += ax * ax; mx.x = fmaxf(mx.x, ax);                  \
        sum.y += ay; sq.y += ay * ay; mx.y = fmaxf(mx.y, ay);                  \
        sum.z += az; sq.z += az * az; mx.z = fmaxf(mx.z, az);                  \
        sum.w += aw; sq.w += aw * aw; mx.w = fmaxf(mx.w, aw);                  \
    }

// Full 5-stage reduce of sum/sq/mx across lanes differing in bits 1..5.
#define WREDUCE()                                                              \
    _Pragma("unroll")                                                          \
    for (int m = 2; m <= 32; m <<= 1) {                                        \
        sum.x += __shfl_xor(sum.x, m, 64);                                     \
        sum.y += __shfl_xor(sum.y, m, 64);                                     \
        sum.z += __shfl_xor(sum.z, m, 64);                                     \
        sum.w += __shfl_xor(sum.w, m, 64);                                     \
        sq.x  += __shfl_xor(sq.x,  m, 64);                                     \
        sq.y  += __shfl_xor(sq.y,  m, 64);                                     \
        sq.z  += __shfl_xor(sq.z,  m, 64);                                     \
        sq.w  += __shfl_xor(sq.w,  m, 64);                                     \
        mx.x = fmaxf(mx.x, __shfl_xor(mx.x, m, 64));                           \
        mx.y = fmaxf(mx.y, __shfl_xor(mx.y, m, 64));                           \
        mx.z = fmaxf(mx.z, __shfl_xor(mx.z, m, 64));                           \
        mx.w = fmaxf(mx.w, __shfl_xor(mx.w, m, 64));                           \
    }

// One WAVE per TWO ADJACENT frustums, processed SEQUENTIALLY (vs R13's interleaved).
// One search serves both (s1 = e0 = s0 + counts[f0]). f1's batch loads are issued
// between f0's accumulate and f0's reduce -> f1 HBM latency hides under f0's
// reduce+norm+store (~1000 cy). Each segment's pipeline is the clean R19 one.
__global__ __launch_bounds__(256) void k_pair(
    const float* __restrict__ pc, const int* __restrict__ i_frustum,
    const float* __restrict__ counts, int n, int F,
    float* __restrict__ out_mean, float* __restrict__ out_std,
    float* __restrict__ out_max, float* __restrict__ out_pcn)
{
    const int wid = (blockIdx.x * blockDim.x + threadIdx.x) >> 6;  // global wave id
    const int f0 = wid * 2;
    if (f0 >= F) return;                                           // wave-uniform exit
    const int f1 = f0 + 1;
    const int lane = threadIdx.x & 63;

    const float c0f = counts[f0];
    const float c1f = (f1 < F) ? counts[f1] : 0.0f;
    const int s0 = wave_lower_bound(i_frustum, n, f0, lane);
    const int e0 = s0 + (int)c0f;
    const int e1 = e0 + (int)c1f;

    const float4* __restrict__ pc4 = reinterpret_cast<const float4*>(pc);
    v4f* __restrict__ out4 = reinterpret_cast<v4f*>(out_pcn);

    const int b0 = s0 * 2, E0 = e0 * 2;       // f0 float4 range
    const int b1 = E0,     E1 = e1 * 2;       // f1 float4 range (adjacent)
    const int lim0 = max(E0 - 1, 0);
    const int lim1 = max(E1 - 1, 0);

    float4 ca[CACHE], cb[CACHE];

    // f0 batch loads (clamped, unconditional).
    {
        int k = b0 + lane;
        #pragma unroll
        for (int u = 0; u < CACHE; ++u) { ca[u] = pc4[min(k, lim0)]; k += 64; }
    }

    float4 sum = {0,0,0,0}, sq = {0,0,0,0}, mx = {0,0,0,0};
    // f0 accumulate (consumes ca as it arrives).
    {
        int k = b0 + lane;
        #pragma unroll
        for (int u = 0; u < CACHE; ++u) { ACC(ca[u], k, E0); k += 64; }
        for (int kk = b0 + lane + CACHE * 64; kk < E0; kk += 64) {  // tail >192 pts
            float4 v = pc4[kk]; ACC(v, kk, E0);
        }
    }

    // Issue f1 batch loads NOW -> latency hides under f0 reduce+norm+store.
    {
        int k = b1 + lane;
        #pragma unroll
        for (int u = 0; u < CACHE; ++u) { cb[u] = pc4[min(k, lim1)]; k += 64; }
    }

    // f0 reduce + stats + normalize + stores.
    WREDUCE();
    {
        const float invc = 1.0f / fmaxf(c0f, 1.0f);
        float4 mean, sd, dv;
        mean.x = sum.x * invc; mean.y = sum.y * invc;
        mean.z = sum.z * invc; mean.w = sum.w * invc;
        float vx = fmaxf(sq.x * invc - mean.x * mean.x, 0.0f);
        float vy = fmaxf(sq.y * invc - mean.y * mean.y, 0.0f);
        float vz = fmaxf(sq.z * invc - mean.z * mean.z, 0.0f);
        float vw = fmaxf(sq.w * invc - mean.w * mean.w, 0.0f);
        sd.x = sqrtf(vx); sd.y = sqrtf(vy); sd.z = sqrtf(vz); sd.w = sqrtf(vw);
        dv.x = 1.0f / (sd.x > 0.f ? sd.x : 1.f);
        dv.y = 1.0f / (sd.y > 0.f ? sd.y : 1.f);
        dv.z = 1.0f / (sd.z > 0.f ? sd.z : 1.f);
        dv.w = 1.0f / (sd.w > 0.f ? sd.w : 1.f);
        if (lane < 2) {
            reinterpret_cast<float4*>(out_mean + (size_t)f0 * NCH)[lane] = mean;
            reinterpret_cast<float4*>(out_std  + (size_t)f0 * NCH)[lane] = sd;
            reinterpret_cast<float4*>(out_max  + (size_t)f0 * NCH)[lane] = mx;
        }
        int k = b0 + lane;
        #pragma unroll
        for (int u = 0; u < CACHE; ++u) {
            if (k < E0) {
                v4f o = norm4(ca[u], mean, dv);
                __builtin_nontemporal_store(o, &out4[k]);
            }
            k += 64;
        }
        for (int kk = b0 + lane + CACHE * 64; kk < E0; kk += 64) {  // tail
            v4f o = norm4(pc4[kk], mean, dv);
            __builtin_nontemporal_store(o, &out4[kk]);
        }
    }

    // f1 accumulate + reduce + stats + normalize + stores.
    sum = {0,0,0,0}; sq = {0,0,0,0}; mx = {0,0,0,0};
    {
        int k = b1 + lane;
        #pragma unroll
        for (int u = 0; u < CACHE; ++u) { ACC(cb[u], k, E1); k += 64; }
        for (int kk = b1 + lane + CACHE * 64; kk < E1; kk += 64) {  // tail
            float4 v = pc4[kk]; ACC(v, kk, E1);
        }
    }
    WREDUCE();
    {
        const float invc = 1.0f / fmaxf(c1f, 1.0f);
        float4 mean, sd, dv;
        mean.x = sum.x * invc; mean.y = sum.y * invc;
        mean.z = sum.z * invc; mean.w = sum.w * invc;
        float vx = fmaxf(sq.x * invc - mean.x * mean.x, 0.0f);
        float vy = fmaxf(sq.y * invc - mean.y * mean.y, 0.0f);
        float vz = fmaxf(sq.z * invc - mean.z * mean.z, 0.0f);
        float vw = fmaxf(sq.w * invc - mean.w * mean.w, 0.0f);
        sd.x = sqrtf(vx); sd.y = sqrtf(vy); sd.z = sqrtf(vz); sd.w = sqrtf(vw);
        dv.x = 1.0f / (sd.x > 0.f ? sd.x : 1.f);
        dv.y = 1.0f / (sd.y > 0.f ? sd.y : 1.f);
        dv.z = 1.0f / (sd.z > 0.f ? sd.z : 1.f);
        dv.w = 1.0f / (sd.w > 0.f ? sd.w : 1.f);
        if (lane < 2 && f1 < F) {
            reinterpret_cast<float4*>(out_mean + (size_t)f1 * NCH)[lane] = mean;
            reinterpret_cast<float4*>(out_std  + (size_t)f1 * NCH)[lane] = sd;
            reinterpret_cast<float4*>(out_max  + (size_t)f1 * NCH)[lane] = mx;
        }
        int k = b1 + lane;
        #pragma unroll
        for (int u = 0; u < CACHE; ++u) {
            if (k < E1) {
                v4f o = norm4(cb[u], mean, dv);
                __builtin_nontemporal_store(o, &out4[k]);
            }
            k += 64;
        }
        for (int kk = b1 + lane + CACHE * 64; kk < E1; kk += 64) {  // tail
            v4f o = norm4(pc4[kk], mean, dv);
            __builtin_nontemporal_store(o, &out4[kk]);
        }
    }
}

extern "C" void kernel_launch(void* const* d_in, const int* in_sizes, int n_in,
                              void* d_out, int out_size, void* d_ws, size_t ws_size,
                              hipStream_t stream) {
    const float* pc        = (const float*)d_in[0];
    const int*   i_frustum = (const int*)d_in[1];
    const float* counts    = (const float*)d_in[3];

    int n = in_sizes[0] / NCH;   // 2,000,000 points
    int F = in_sizes[3];         // 14,400 frustums

    float* out_mean = (float*)d_out;
    float* out_std  = out_mean + (size_t)F * NCH;
    float* out_max  = out_std  + (size_t)F * NCH;
    float* out_pcn  = out_max  + (size_t)F * NCH;

    int nwaves = (F + 1) / 2;    // one wave per 2 adjacent frustums
    int waves_per_block = 256 / 64;
    int blocks = (nwaves + waves_per_block - 1) / waves_per_block;
    k_pair<<<blocks, 256, 0, stream>>>(pc, i_frustum, counts, n, F,
                                       out_mean, out_std, out_max, out_pcn);
}

// Round 23
// 29.218 us; speedup vs baseline: 1.1487x; 1.0082x over previous
//
#include <hip/hip_runtime.h>

#define NCH 8
#define CACHE 6   // float4 per lane per segment -> 384 slots; covers <=192 pts (max ~190)

typedef float v4f __attribute__((ext_vector_type(4)));

__device__ __forceinline__ v4f norm4(const float4& v, const float4& m, const float4& d) {
    v4f o;
    o.x = (v.x - m.x) * d.x;
    o.y = (v.y - m.y) * d.y;
    o.z = (v.z - m.z) * d.z;
    o.w = (v.w - m.w) * d.w;
    return o;
}

// Wave-cooperative lower_bound: smallest idx with a[idx] >= key. 4 memory rounds for n=2M.
__device__ __forceinline__ int wave_lower_bound(const int* __restrict__ a, int n, int key,
                                                int lane) {
    int lo = 0, len = n;
    while (len > 64) {
        int step = (len + 63) >> 6;                       // ceil(len/64)
        int p = lo + lane * step;
        int v = (p < lo + len) ? a[p] : 0x7fffffff;
        unsigned long long bal = __ballot(v < key);
        int cnt = __popcll(bal);                          // preds form a prefix (sorted)
        if (cnt == 0) return lo;
        int nlo = lo + (cnt - 1) * step + 1;
        int nhi = lo + len;
        int cap = lo + cnt * step;
        if (cnt < 64 && cap < nhi) nhi = cap;
        lo = nlo; len = nhi - nlo;
    }
    int v = (lane < len) ? a[lo + lane] : 0x7fffffff;
    unsigned long long bal = __ballot(v < key);
    return lo + __popcll(bal);
}

// Masked accumulate of one cached segment slice.
#define ACC(creg, kvar, Evar)                                                  \
    {                                                                          \
        const bool in = (kvar) < (Evar);                                       \
        float ax = in ? (creg).x : 0.f, ay = in ? (creg).y : 0.f;              \
        float az = in ? (creg).z : 0.f, aw = in ? (creg).w : 0.f;              \
        sum.x += ax; sq.x += ax * ax; mx.x = fmaxf(mx.x, ax);                  \
        sum.y += ay; sq.y += ay * ay; mx.y = fmaxf(mx.y, ay);                  \
        sum.z += az; sq.z += az * az; mx.z = fmaxf(mx.z, az);                  \
        sum.w += aw; sq.w += aw * aw; mx.w = fmaxf(mx.w, aw);                  \
    }

// Full 5-stage reduce of sum/sq/mx across lanes differing in bits 1..5.
#define WREDUCE()                                                              \
    _Pragma("unroll")                                                          \
    for (int m = 2; m <= 32; m <<= 1) {                                        \
        sum.x += __shfl_xor(sum.x, m, 64);                                     \
        sum.y += __shfl_xor(sum.y, m, 64);                                     \
        sum.z += __shfl_xor(sum.z, m, 64);                                     \
        sum.w += __shfl_xor(sum.w, m, 64);                                     \
        sq.x  += __shfl_xor(sq.x,  m, 64);                                     \
        sq.y  += __shfl_xor(sq.y,  m, 64);                                     \
        sq.z  += __shfl_xor(sq.z,  m, 64);                                     \
        sq.w  += __shfl_xor(sq.w,  m, 64);                                     \
        mx.x = fmaxf(mx.x, __shfl_xor(mx.x, m, 64));                           \
        mx.y = fmaxf(mx.y, __shfl_xor(mx.y, m, 64));                           \
        mx.z = fmaxf(mx.z, __shfl_xor(mx.z, m, 64));                           \
        mx.w = fmaxf(mx.w, __shfl_xor(mx.w, m, 64));                           \
    }

// One WAVE per TWO ADJACENT frustums (R22 base). R23 single-variable change:
// BOTH segments' loads issue back-to-back up-front (12 outstanding float4/lane)
// before any accumulate -- the first clean test of the per-wave-MLP hypothesis
// (R13 had the depth but branchy accumulate; R22 had clean pipes but depth 6).
__global__ __launch_bounds__(256) void k_pair(
    const float* __restrict__ pc, const int* __restrict__ i_frustum,
    const float* __restrict__ counts, int n, int F,
    float* __restrict__ out_mean, float* __restrict__ out_std,
    float* __restrict__ out_max, float* __restrict__ out_pcn)
{
    const int wid = (blockIdx.x * blockDim.x + threadIdx.x) >> 6;  // global wave id
    const int f0 = wid * 2;
    if (f0 >= F) return;                                           // wave-uniform exit
    const int f1 = f0 + 1;
    const int lane = threadIdx.x & 63;

    const float c0f = counts[f0];
    const float c1f = (f1 < F) ? counts[f1] : 0.0f;
    const int s0 = wave_lower_bound(i_frustum, n, f0, lane);
    const int e0 = s0 + (int)c0f;
    const int e1 = e0 + (int)c1f;

    const float4* __restrict__ pc4 = reinterpret_cast<const float4*>(pc);
    v4f* __restrict__ out4 = reinterpret_cast<v4f*>(out_pcn);

    const int b0 = s0 * 2, E0 = e0 * 2;       // f0 float4 range
    const int b1 = E0,     E1 = e1 * 2;       // f1 float4 range (adjacent)
    const int lim0 = max(E0 - 1, 0);
    const int lim1 = max(E1 - 1, 0);

    float4 ca[CACHE], cb[CACHE];

    // Issue ALL loads for BOTH segments back-to-back: 12 outstanding per lane.
    {
        int k = b0 + lane;
        #pragma unroll
        for (int u = 0; u < CACHE; ++u) { ca[u] = pc4[min(k, lim0)]; k += 64; }
    }
    {
        int k = b1 + lane;
        #pragma unroll
        for (int u = 0; u < CACHE; ++u) { cb[u] = pc4[min(k, lim1)]; k += 64; }
    }

    float4 sum = {0,0,0,0}, sq = {0,0,0,0}, mx = {0,0,0,0};
    // f0 accumulate.
    {
        int k = b0 + lane;
        #pragma unroll
        for (int u = 0; u < CACHE; ++u) { ACC(ca[u], k, E0); k += 64; }
        for (int kk = b0 + lane + CACHE * 64; kk < E0; kk += 64) {  // tail >192 pts
            float4 v = pc4[kk]; ACC(v, kk, E0);
        }
    }

    // f0 reduce + stats + normalize + stores.
    WREDUCE();
    {
        const float invc = 1.0f / fmaxf(c0f, 1.0f);
        float4 mean, sd, dv;
        mean.x = sum.x * invc; mean.y = sum.y * invc;
        mean.z = sum.z * invc; mean.w = sum.w * invc;
        float vx = fmaxf(sq.x * invc - mean.x * mean.x, 0.0f);
        float vy = fmaxf(sq.y * invc - mean.y * mean.y, 0.0f);
        float vz = fmaxf(sq.z * invc - mean.z * mean.z, 0.0f);
        float vw = fmaxf(sq.w * invc - mean.w * mean.w, 0.0f);
        sd.x = sqrtf(vx); sd.y = sqrtf(vy); sd.z = sqrtf(vz); sd.w = sqrtf(vw);
        dv.x = 1.0f / (sd.x > 0.f ? sd.x : 1.f);
        dv.y = 1.0f / (sd.y > 0.f ? sd.y : 1.f);
        dv.z = 1.0f / (sd.z > 0.f ? sd.z : 1.f);
        dv.w = 1.0f / (sd.w > 0.f ? sd.w : 1.f);
        if (lane < 2) {
            reinterpret_cast<float4*>(out_mean + (size_t)f0 * NCH)[lane] = mean;
            reinterpret_cast<float4*>(out_std  + (size_t)f0 * NCH)[lane] = sd;
            reinterpret_cast<float4*>(out_max  + (size_t)f0 * NCH)[lane] = mx;
        }
        int k = b0 + lane;
        #pragma unroll
        for (int u = 0; u < CACHE; ++u) {
            if (k < E0) {
                v4f o = norm4(ca[u], mean, dv);
                __builtin_nontemporal_store(o, &out4[k]);
            }
            k += 64;
        }
        for (int kk = b0 + lane + CACHE * 64; kk < E0; kk += 64) {  // tail
            v4f o = norm4(pc4[kk], mean, dv);
            __builtin_nontemporal_store(o, &out4[kk]);
        }
    }

    // f1 accumulate + reduce + stats + normalize + stores.
    sum = {0,0,0,0}; sq = {0,0,0,0}; mx = {0,0,0,0};
    {
        int k = b1 + lane;
        #pragma unroll
        for (int u = 0; u < CACHE; ++u) { ACC(cb[u], k, E1); k += 64; }
        for (int kk = b1 + lane + CACHE * 64; kk < E1; kk += 64) {  // tail
            float4 v = pc4[kk]; ACC(v, kk, E1);
        }
    }
    WREDUCE();
    {
        const float invc = 1.0f / fmaxf(c1f, 1.0f);
        float4 mean, sd, dv;
        mean.x = sum.x * invc; mean.y = sum.y * invc;
        mean.z = sum.z * invc; mean.w = sum.w * invc;
        float vx = fmaxf(sq.x * invc - mean.x * mean.x, 0.0f);
        float vy = fmaxf(sq.y * invc - mean.y * mean.y, 0.0f);
        float vz = fmaxf(sq.z * invc - mean.z * mean.z, 0.0f);
        float vw = fmaxf(sq.w * invc - mean.w * mean.w, 0.0f);
        sd.x = sqrtf(vx); sd.y = sqrtf(vy); sd.z = sqrtf(vz); sd.w = sqrtf(vw);
        dv.x = 1.0f / (sd.x > 0.f ? sd.x : 1.f);
        dv.y = 1.0f / (sd.y > 0.f ? sd.y : 1.f);
        dv.z = 1.0f / (sd.z > 0.f ? sd.z : 1.f);
        dv.w = 1.0f / (sd.w > 0.f ? sd.w : 1.f);
        if (lane < 2 && f1 < F) {
            reinterpret_cast<float4*>(out_mean + (size_t)f1 * NCH)[lane] = mean;
            reinterpret_cast<float4*>(out_std  + (size_t)f1 * NCH)[lane] = sd;
            reinterpret_cast<float4*>(out_max  + (size_t)f1 * NCH)[lane] = mx;
        }
        int k = b1 + lane;
        #pragma unroll
        for (int u = 0; u < CACHE; ++u) {
            if (k < E1) {
                v4f o = norm4(cb[u], mean, dv);
                __builtin_nontemporal_store(o, &out4[k]);
            }
            k += 64;
        }
        for (int kk = b1 + lane + CACHE * 64; kk < E1; kk += 64) {  // tail
            v4f o = norm4(pc4[kk], mean, dv);
            __builtin_nontemporal_store(o, &out4[kk]);
        }
    }
}

extern "C" void kernel_launch(void* const* d_in, const int* in_sizes, int n_in,
                              void* d_out, int out_size, void* d_ws, size_t ws_size,
                              hipStream_t stream) {
    const float* pc        = (const float*)d_in[0];
    const int*   i_frustum = (const int*)d_in[1];
    const float* counts    = (const float*)d_in[3];

    int n = in_sizes[0] / NCH;   // 2,000,000 points
    int F = in_sizes[3];         // 14,400 frustums

    float* out_mean = (float*)d_out;
    float* out_std  = out_mean + (size_t)F * NCH;
    float* out_max  = out_std  + (size_t)F * NCH;
    float* out_pcn  = out_max  + (size_t)F * NCH;

    int nwaves = (F + 1) / 2;    // one wave per 2 adjacent frustums
    int waves_per_block = 256 / 64;
    int blocks = (nwaves + waves_per_block - 1) / waves_per_block;
    k_pair<<<blocks, 256, 0, stream>>>(pc, i_frustum, counts, n, F,
                                       out_mean, out_std, out_max, out_pcn);
}